// Round 1
// baseline (305.825 us; speedup 1.0000x reference)
//
#include <hip/hip_runtime.h>
#include <hip/hip_bf16.h>
#include <cstdint>
#include <cstddef>

// Problem constants (fixed by the reference):
#define TTOK 4096
#define DM   1024
#define NE   8
#define KTOP 2
#define FFD  1024
#define CPER 1024       // TTOK*KTOP/NE tokens per expert (balanced)
#define MROWS 12288     // 8192 MoE permuted rows + 4096 shared rows
#define NT   32         // R10: K / 32 tiles (BK=32 for double-buffer in same LDS)

typedef __attribute__((ext_vector_type(8))) short frag8;   // 8 bf16 = 4 VGPRs
typedef __attribute__((ext_vector_type(4))) float f32x4;   // MFMA accumulator

static __device__ __forceinline__ unsigned short f2bf(float f) {
  unsigned int u = __float_as_uint(f);
  u += 0x7fff + ((u >> 16) & 1);     // round-to-nearest-even
  return (unsigned short)(u >> 16);
}
static __device__ __forceinline__ float bf2f(unsigned short u) {
  return __uint_as_float((unsigned int)u << 16);
}

static __device__ __forceinline__ void gld_lds16(const unsigned short* g, unsigned short* l) {
  __builtin_amdgcn_global_load_lds(
      (const __attribute__((address_space(1))) unsigned int*)g,
      (__attribute__((address_space(3))) unsigned int*)l,
      16, 0, 0);
}

// R10: BK=32 tile = 128 rows x 4 segments of 16B. global_load_lds writes LINEAR
// LDS (wave base + lane*16B; m104/m108), so the bank swizzle lives on the
// GLOBAL side: linear slot seg holds global column segment cs=(seg&3)^((r>>1)&3).
// XOR is involutive -> reader finds global (r,c) at lds_slot32(r,c). Analysis:
// frag read lanes lr=0..15 at rows r0+lr, bank = (16*lr + 4*(c^((lr>>1)&3)))%32
// -> lanes 0..7 hit 8 distinct banks, lanes 8..15 repeat = exactly 2-way, which
// is FREE (m136: 1.02x). (The old c^(r&7) scheme needed 8 segs; with 4 segs it
// would give 4-way on rows 0,4,8,12.)
static __device__ __forceinline__ int lds_slot32(int r, int c) {
  return r * 4 + (c ^ ((r >> 1) & 3));
}

// XCD-locality block swizzle for grid(8,96): XCD = linear_id % 8; each XCD
// owns 12 consecutive y-tiles (all x). R5 measured FETCH 117->54.6 MB.
static __device__ __forceinline__ void swizzle_xy(int& x, int& y) {
  int L = blockIdx.y * 8 + blockIdx.x;
  int xcd = L & 7;
  int s = L >> 3;                    // 0..95
  y = xcd * 12 + s % 12;
  x = s / 12;
}

// ---------------- fused routing + convert + shared gate ----------------
// 1024 blocks x 256 threads; one wave per row (4 rows/block) converts hidden
// -> bf16 and computes the sigmoid gate. Blocks 0..31 additionally run the
// routing (dense atomics from 8192 threads, ~3 us; R7: never spread these
// one-per-block).
__global__ void prep_kernel(const float* __restrict__ x, const float* __restrict__ gw,
                            const int* __restrict__ idx, const float* __restrict__ tw,
                            int* __restrict__ cnt, int* __restrict__ rowsrc,
                            int* __restrict__ inv, float* __restrict__ rowscale,
                            unsigned short* __restrict__ xb) {
  if (blockIdx.x < 32) {
    int i = blockIdx.x * 256 + threadIdx.x;      // i < TTOK*KTOP
    int e = idx[i];
    int pos = atomicAdd(&cnt[e], 1);             // order within expert irrelevant
    int j = e * CPER + pos;
    rowsrc[j] = i >> 1;                          // token id (KTOP==2)
    rowscale[j] = tw[i];                         // topk weight -> gemm2 epilogue
    inv[i] = j;                                  // inverse perm for combine
    if (i < TTOK) rowsrc[8192 + i] = i;          // shared rows: identity
  }
  int row = blockIdx.x * 4 + (threadIdx.x >> 6);
  int lane = threadIdx.x & 63;
  const float4* xr = (const float4*)(x + (size_t)row * 1024);
  const float4* wr = (const float4*)gw;
  ushort4* ob = (ushort4*)(xb + (size_t)row * 1024);
  float s = 0.f;
#pragma unroll
  for (int c = 0; c < 4; ++c) {
    int k = lane + 64 * c;
    float4 v = xr[k];
    float4 g = wr[k];
    s += v.x * g.x + v.y * g.y + v.z * g.z + v.w * g.w;
    ushort4 o;
    o.x = f2bf(v.x); o.y = f2bf(v.y); o.z = f2bf(v.z); o.w = f2bf(v.w);
    ob[k] = o;
  }
#pragma unroll
  for (int off = 32; off; off >>= 1) s += __shfl_down(s, off);
  if (lane == 0) rowscale[8192 + row] = 1.f / (1.f + __expf(-s));
}

// ---------------- transpose + cast all 27 1024x1024 weight mats ----------------
// 64x64 tiles, float4 reads, ushort4 writes, LDS stride 65 (odd -> <=2-way).
// Outputs packed [9][1024][1024] per matrix kind; index 8 = shared expert.
__global__ void transw_kernel(const float* __restrict__ wg, const float* __restrict__ wu,
                              const float* __restrict__ wd, const float* __restrict__ sg,
                              const float* __restrict__ su, const float* __restrict__ sd,
                              unsigned short* __restrict__ owg, unsigned short* __restrict__ owu,
                              unsigned short* __restrict__ owd) {
  int z = blockIdx.z;
  const float* src; unsigned short* dst;
  if (z < 8)       { src = wg + (size_t)z * 1048576;        dst = owg + (size_t)z * 1048576; }
  else if (z < 16) { src = wu + (size_t)(z - 8) * 1048576;  dst = owu + (size_t)(z - 8) * 1048576; }
  else if (z < 24) { src = wd + (size_t)(z - 16) * 1048576; dst = owd + (size_t)(z - 16) * 1048576; }
  else if (z == 24){ src = sg; dst = owg + (size_t)8 * 1048576; }
  else if (z == 25){ src = su; dst = owu + (size_t)8 * 1048576; }
  else             { src = sd; dst = owd + (size_t)8 * 1048576; }
  __shared__ float tile[64][65];
  int bx = blockIdx.x * 64;   // src col base
  int by = blockIdx.y * 64;   // src row base
  int c4 = threadIdx.x & 15;  // float4 chunk within row
  int r0 = threadIdx.x >> 4;  // 0..15
#pragma unroll
  for (int i = 0; i < 4; ++i) {
    int r = r0 + 16 * i;
    float4 v = *(const float4*)&src[(size_t)(by + r) * 1024 + bx + c4 * 4];
    tile[r][c4 * 4 + 0] = v.x; tile[r][c4 * 4 + 1] = v.y;
    tile[r][c4 * 4 + 2] = v.z; tile[r][c4 * 4 + 3] = v.w;
  }
  __syncthreads();
#pragma unroll
  for (int i = 0; i < 4; ++i) {
    int f = r0 + 16 * i;       // dst row = src col bx+f
    ushort4 o;
    o.x = f2bf(tile[c4 * 4 + 0][f]);
    o.y = f2bf(tile[c4 * 4 + 1][f]);
    o.z = f2bf(tile[c4 * 4 + 2][f]);
    o.w = f2bf(tile[c4 * 4 + 3][f]);
    *(ushort4*)&dst[(size_t)(bx + f) * 1024 + by + c4 * 4] = o;
  }
}

// Expert id for a 128-row M-block: y<64 -> MoE expert y/8; else shared (8).
static __device__ __forceinline__ int eid_of(int y) { return (y < 64) ? (y >> 3) : 8; }

// ---------------- GEMM1: H = silu(A @ Wg) * (A @ Wu), bf16 out ----------------
// R10: double-buffered BK=32 pipeline with COUNTED vmcnt (T3+T4). Per tile:
//   stage(t+1 -> buf^1)  [6 gld_lds/thread]
//   s_waitcnt vmcnt(6)   <- waits tile t's loads only; t+1's stay IN FLIGHT
//   s_barrier; ds_read + 32 MFMA (setprio(1) around cluster, T5)
//   s_barrier            <- protects buf^1 before next iter overwrites it
// Same 48KB LDS as R9's BK=64 single-buffer -> keeps 2 blocks/CU. Old structure
// drained vmcnt(0) inside __syncthreads with loads issued AFTER compute; that
// exposed full global->LDS latency per K-tile (MfmaUtil 33%).
__global__ __launch_bounds__(256, 2) void gemm1_kernel(
    const unsigned short* __restrict__ A, const int* __restrict__ rowsrc,
    const unsigned short* __restrict__ Bg, const unsigned short* __restrict__ Bu,
    unsigned short* __restrict__ H) {
  __shared__ __align__(16) unsigned short As[2][128 * 32];
  __shared__ __align__(16) unsigned short Bgs[2][128 * 32];
  __shared__ __align__(16) unsigned short Bus[2][128 * 32];
  int tid = threadIdx.x;
  int bx, by;
  swizzle_xy(bx, by);
  int e = eid_of(by);
  int row0 = by * 128;
  int col0 = bx * 128;
  const unsigned short* Bge = Bg + (size_t)e * 1048576;
  const unsigned short* Bue = Bu + (size_t)e * 1048576;

  // per-thread staging sources (fixed across K): 2 segs each, global-side swizzle
  const unsigned short *pA[2], *pBg[2], *pBu[2];
#pragma unroll
  for (int it = 0; it < 2; ++it) {
    int seg = it * 256 + tid;
    int r = seg >> 2;
    int cs = (seg & 3) ^ ((r >> 1) & 3);
    pA[it]  = A   + (size_t)rowsrc[row0 + r] * 1024 + cs * 8;
    pBg[it] = Bge + (size_t)(col0 + r) * 1024 + cs * 8;
    pBu[it] = Bue + (size_t)(col0 + r) * 1024 + cs * 8;
  }

  int wave = tid >> 6, lane = tid & 63;
  int wm = wave >> 1, wn = wave & 1;             // 2x2 wave grid, 64x64 per wave
  int lr = lane & 15, q = lane >> 4;

  f32x4 accg[4][4], accu[4][4];
#pragma unroll
  for (int i = 0; i < 4; ++i)
#pragma unroll
    for (int j = 0; j < 4; ++j) {
      accg[i][j] = (f32x4){0.f, 0.f, 0.f, 0.f};
      accu[i][j] = (f32x4){0.f, 0.f, 0.f, 0.f};
    }

  // prologue: tile 0 -> buf 0
#pragma unroll
  for (int it = 0; it < 2; ++it) {
    int off = (it * 256 + tid) * 8;
    gld_lds16(pA[it],  As[0] + off);
    gld_lds16(pBg[it], Bgs[0] + off);
    gld_lds16(pBu[it], Bus[0] + off);
  }

#pragma unroll 2
  for (int t = 0; t < NT; ++t) {
    int cur = t & 1;
    if (t + 1 < NT) {
      int kt = (t + 1) * 32;
#pragma unroll
      for (int it = 0; it < 2; ++it) {
        int off = (it * 256 + tid) * 8;
        gld_lds16(pA[it] + kt,  As[cur ^ 1] + off);
        gld_lds16(pBg[it] + kt, Bgs[cur ^ 1] + off);
        gld_lds16(pBu[it] + kt, Bus[cur ^ 1] + off);
      }
      asm volatile("s_waitcnt vmcnt(6)" ::: "memory");   // tile t landed; t+1 in flight
    } else {
      asm volatile("s_waitcnt vmcnt(0)" ::: "memory");   // last tile: drain
    }
    __builtin_amdgcn_s_barrier();

    frag8 a[4], b0[4], b1[4];
#pragma unroll
    for (int i = 0; i < 4; ++i) {
      int r = wm * 64 + i * 16 + lr;
      a[i] = *(const frag8*)&As[cur][lds_slot32(r, q) * 8];
    }
#pragma unroll
    for (int j = 0; j < 4; ++j) {
      int r = wn * 64 + j * 16 + lr;
      b0[j] = *(const frag8*)&Bgs[cur][lds_slot32(r, q) * 8];
      b1[j] = *(const frag8*)&Bus[cur][lds_slot32(r, q) * 8];
    }
    __builtin_amdgcn_s_setprio(1);
#pragma unroll
    for (int i = 0; i < 4; ++i)
#pragma unroll
      for (int j = 0; j < 4; ++j) {
        accg[i][j] = __builtin_amdgcn_mfma_f32_16x16x32_bf16(a[i], b0[j], accg[i][j], 0, 0, 0);
        accu[i][j] = __builtin_amdgcn_mfma_f32_16x16x32_bf16(a[i], b1[j], accu[i][j], 0, 0, 0);
      }
    __builtin_amdgcn_s_setprio(0);
    __builtin_amdgcn_s_barrier();                // all waves done with buf[cur]
  }
#pragma unroll
  for (int i = 0; i < 4; ++i)
#pragma unroll
    for (int j = 0; j < 4; ++j)
#pragma unroll
      for (int r = 0; r < 4; ++r) {
        int m = row0 + wm * 64 + i * 16 + q * 4 + r;   // C/D: row=quad*4+reg
        int n = col0 + wn * 64 + j * 16 + lr;          //       col=lane&15
        float gv = accg[i][j][r];
        float hv = gv / (1.f + __expf(-gv)) * accu[i][j][r];
        H[(size_t)m * 1024 + n] = f2bf(hv);
      }
}

// ---------------- GEMM2: Y = rowscale * (A @ Wd), bf16 out ----------------
// R10: same counted-vmcnt double-buffer pipeline; 4 loads/thread/tile -> vmcnt(4).
// LDS 32KB/block, 2 blocks/CU.
__global__ __launch_bounds__(256, 2) void gemm2_kernel(
    const unsigned short* __restrict__ A, const unsigned short* __restrict__ B,
    const float* __restrict__ rowscale, unsigned short* __restrict__ Y) {
  __shared__ __align__(16) unsigned short As[2][128 * 32];
  __shared__ __align__(16) unsigned short Bs[2][128 * 32];
  int tid = threadIdx.x;
  int bx, by;
  swizzle_xy(bx, by);
  int e = eid_of(by);
  int row0 = by * 128;
  int col0 = bx * 128;
  const unsigned short* Be = B + (size_t)e * 1048576;

  const unsigned short *pA[2], *pB[2];
#pragma unroll
  for (int it = 0; it < 2; ++it) {
    int seg = it * 256 + tid;
    int r = seg >> 2;
    int cs = (seg & 3) ^ ((r >> 1) & 3);
    pA[it] = A  + (size_t)(row0 + r) * 1024 + cs * 8;
    pB[it] = Be + (size_t)(col0 + r) * 1024 + cs * 8;
  }

  int wave = tid >> 6, lane = tid & 63;
  int wm = wave >> 1, wn = wave & 1;
  int lr = lane & 15, q = lane >> 4;

  f32x4 acc[4][4];
#pragma unroll
  for (int i = 0; i < 4; ++i)
#pragma unroll
    for (int j = 0; j < 4; ++j) acc[i][j] = (f32x4){0.f, 0.f, 0.f, 0.f};

  // prologue: tile 0 -> buf 0
#pragma unroll
  for (int it = 0; it < 2; ++it) {
    int off = (it * 256 + tid) * 8;
    gld_lds16(pA[it], As[0] + off);
    gld_lds16(pB[it], Bs[0] + off);
  }

#pragma unroll 2
  for (int t = 0; t < NT; ++t) {
    int cur = t & 1;
    if (t + 1 < NT) {
      int kt = (t + 1) * 32;
#pragma unroll
      for (int it = 0; it < 2; ++it) {
        int off = (it * 256 + tid) * 8;
        gld_lds16(pA[it] + kt, As[cur ^ 1] + off);
        gld_lds16(pB[it] + kt, Bs[cur ^ 1] + off);
      }
      asm volatile("s_waitcnt vmcnt(4)" ::: "memory");
    } else {
      asm volatile("s_waitcnt vmcnt(0)" ::: "memory");
    }
    __builtin_amdgcn_s_barrier();

    frag8 a[4], b[4];
#pragma unroll
    for (int i = 0; i < 4; ++i) {
      int r = wm * 64 + i * 16 + lr;
      a[i] = *(const frag8*)&As[cur][lds_slot32(r, q) * 8];
    }
#pragma unroll
    for (int j = 0; j < 4; ++j) {
      int r = wn * 64 + j * 16 + lr;
      b[j] = *(const frag8*)&Bs[cur][lds_slot32(r, q) * 8];
    }
    __builtin_amdgcn_s_setprio(1);
#pragma unroll
    for (int i = 0; i < 4; ++i)
#pragma unroll
      for (int j = 0; j < 4; ++j)
        acc[i][j] = __builtin_amdgcn_mfma_f32_16x16x32_bf16(a[i], b[j], acc[i][j], 0, 0, 0);
    __builtin_amdgcn_s_setprio(0);
    __builtin_amdgcn_s_barrier();
  }
#pragma unroll
  for (int i = 0; i < 4; ++i)
#pragma unroll
    for (int r = 0; r < 4; ++r) {
      int m = row0 + wm * 64 + i * 16 + q * 4 + r;
      float sc = rowscale[m];
#pragma unroll
      for (int j = 0; j < 4; ++j) {
        int n = col0 + wn * 64 + j * 16 + lr;
        Y[(size_t)m * 1024 + n] = f2bf(sc * acc[i][j][r]);
      }
    }
}

// ---------------- final combine: out[t] = Y[j0] + Y[j1] + Y[8192+t] ----------
// Flat slot mapping, 2 independent slots/thread (R8 lesson: avoid one-row
// blocks).
__global__ void combine_kernel(const unsigned short* __restrict__ Y,
                               const int* __restrict__ inv, float* __restrict__ out) {
  int base = blockIdx.x * 256 + threadIdx.x;
#pragma unroll
  for (int k = 0; k < 2; ++k) {
    int slot = base + k * 524288;                // 2048 blocks * 256 threads
    int t = slot >> 8;
    int c = slot & 255;
    int j0 = inv[2 * t], j1 = inv[2 * t + 1];
    ushort4 a = ((const ushort4*)(Y + (size_t)j0 * 1024))[c];
    ushort4 b = ((const ushort4*)(Y + (size_t)j1 * 1024))[c];
    ushort4 s = ((const ushort4*)(Y + (size_t)(8192 + t) * 1024))[c];
    float4 o;
    o.x = bf2f(a.x) + bf2f(b.x) + bf2f(s.x);
    o.y = bf2f(a.y) + bf2f(b.y) + bf2f(s.y);
    o.z = bf2f(a.z) + bf2f(b.z) + bf2f(s.z);
    o.w = bf2f(a.w) + bf2f(b.w) + bf2f(s.w);
    ((float4*)(out + (size_t)t * 1024))[c] = o;
  }
}

extern "C" void kernel_launch(void* const* d_in, const int* in_sizes, int n_in,
                              void* d_out, int out_size, void* d_ws, size_t ws_size,
                              hipStream_t stream) {
  (void)in_sizes; (void)n_in; (void)out_size; (void)ws_size;
  const float* hidden  = (const float*)d_in[0];
  const float* topk_w  = (const float*)d_in[1];
  const float* w_gate  = (const float*)d_in[2];
  const float* w_up    = (const float*)d_in[3];
  const float* w_down  = (const float*)d_in[4];
  const float* sw_gate = (const float*)d_in[5];
  const float* sw_up   = (const float*)d_in[6];
  const float* sw_down = (const float*)d_in[7];
  const float* sgw     = (const float*)d_in[8];
  const int*   topk_i  = (const int*)d_in[9];
  float* out = (float*)d_out;

  char* p = (char*)d_ws;
  auto alloc = [&](size_t bytes) {
    char* r = p;
    p += (bytes + 255) & ~(size_t)255;
    return r;
  };
  unsigned short* Wg_all = (unsigned short*)alloc((size_t)9 * 1048576 * 2);  // [9][1024][1024]
  unsigned short* Wu_all = (unsigned short*)alloc((size_t)9 * 1048576 * 2);
  unsigned short* Wd_all = (unsigned short*)alloc((size_t)9 * 1048576 * 2);
  unsigned short* Xbf    = (unsigned short*)alloc((size_t)TTOK * 1024 * 2);  // bf16 hidden
  unsigned short* Hall   = (unsigned short*)alloc((size_t)MROWS * 1024 * 2);
  unsigned short* Yall   = (unsigned short*)alloc((size_t)MROWS * 1024 * 2);
  int*   cnt      = (int*)alloc(NE * 4);
  int*   rowsrc   = (int*)alloc((size_t)MROWS * 4);
  int*   inv      = (int*)alloc((size_t)TTOK * KTOP * 4);
  float* rowscale = (float*)alloc((size_t)MROWS * 4);

  hipMemsetAsync(cnt, 0, NE * 4, stream);

  prep_kernel<<<TTOK / 4, 256, 0, stream>>>(hidden, sgw, topk_i, topk_w,
                                            cnt, rowsrc, inv, rowscale, Xbf);
  transw_kernel<<<dim3(16, 16, 27), 256, 0, stream>>>(
      w_gate, w_up, w_down, sw_gate, sw_up, sw_down, Wg_all, Wu_all, Wd_all);

  gemm1_kernel<<<dim3(8, 96), 256, 0, stream>>>(Xbf, rowsrc, Wg_all, Wu_all, Hall);
  gemm2_kernel<<<dim3(8, 96), 256, 0, stream>>>(Hall, Wd_all, rowscale, Yall);
  combine_kernel<<<2048, 256, 0, stream>>>(Yall, inv, out);
}